// Round 1
// baseline (771.541 us; speedup 1.0000x reference)
//
#include <hip/hip_runtime.h>
#include <math.h>

#define BB 32
#define NN 1024
#define DD 768
#define AL 10
#define NC 150
#define CTX 77
#define TD 512
#define SCALE 0.036084391824351615f  /* 768^-0.5 */

// ---------------- text prep: tf = mean over ctx, then L2-normalize ----------------
__global__ void k_textprep(const float* __restrict__ tfeat, float* __restrict__ tfn) {
    int c = blockIdx.x, t = threadIdx.x;  // 150 blocks x 256
    const float* base = tfeat + (size_t)c * CTX * TD;
    float s0 = 0.f, s1 = 0.f;
    for (int j = 0; j < CTX; ++j) {
        s0 += base[j * TD + t];
        s1 += base[j * TD + t + 256];
    }
    s0 *= (1.f / CTX); s1 *= (1.f / CTX);
    __shared__ float red[256];
    red[t] = s0 * s0 + s1 * s1;
    __syncthreads();
    for (int o = 128; o > 0; o >>= 1) { if (t < o) red[t] += red[t + o]; __syncthreads(); }
    float rn = rsqrtf(red[0]);
    tfn[c * TD + t] = s0 * rn;
    tfn[c * TD + t + 256] = s1 * rn;
}

// ---------------- temb = relu(tfn @ wt.T + bt) : (150,512)@(512,768) ----------------
__global__ void k_temb(const float* __restrict__ tfn, const float* __restrict__ wt,
                       const float* __restrict__ bt, float* __restrict__ temb) {
    int c = blockIdx.x, t = threadIdx.x;  // 150 blocks x 256
    __shared__ float row[TD];
    row[t] = tfn[c * TD + t];
    row[t + 256] = tfn[c * TD + t + 256];
    __syncthreads();
    for (int dd = 0; dd < 3; ++dd) {
        int d = dd * 256 + t;
        const float* wr = wt + (size_t)d * TD;
        float acc = bt[d];
        for (int k = 0; k < TD; k += 4) {
            float4 w4 = *reinterpret_cast<const float4*>(wr + k);
            acc += row[k] * w4.x + row[k + 1] * w4.y + row[k + 2] * w4.z + row[k + 3] * w4.w;
        }
        temb[c * DD + d] = fmaxf(acc, 0.f);
    }
}

// ---------------- w_text[c,a] = sigmoid(scale * dot(ag[a], temb[c])) ----------------
__global__ void k_wtext(const float* __restrict__ temb, const float* __restrict__ agent,
                        const int* __restrict__ layerp, float* __restrict__ wtex) {
    int c = blockIdx.x / AL, a = blockIdx.x % AL;
    int l = threadIdx.x;  // 64
    const float* ar = agent + ((size_t)layerp[0] * AL + a) * DD;
    const float* tr = temb + (size_t)c * DD;
    float p = 0.f;
    for (int j = 0; j < 12; ++j) { int d = j * 64 + l; p += ar[d] * tr[d]; }
    #pragma unroll
    for (int o = 1; o < 64; o <<= 1) p += __shfl_xor(p, o);
    if (l == 0) wtex[c * AL + a] = 1.f / (1.f + __expf(-p * SCALE));
}

// ---------------- pooled_text[a,d] = sum_c w[c,a]*temb[c,d] / (sum_c w[c,a]+eps) ----------------
__global__ void k_ptext(const float* __restrict__ temb, const float* __restrict__ wtex,
                        float* __restrict__ ptex) {
    int a = blockIdx.x / 3, dch = blockIdx.x % 3;  // 30 blocks x 256
    int d = dch * 256 + threadIdx.x;
    float num = 0.f, den = 0.f;
    for (int c = 0; c < NC; ++c) {
        float wv = wtex[c * AL + a];
        num += wv * temb[c * DD + d];
        den += wv;
    }
    ptex[a * DD + d] = num / (den + 1e-6f);
}

// ---------------- mtext = pooled_text @ wm.T + bm : (10,768)@(768,768) ----------------
__global__ void k_mtext(const float* __restrict__ ptex, const float* __restrict__ wm,
                        const float* __restrict__ bm, float* __restrict__ mtext) {
    int a = blockIdx.x, t = threadIdx.x;  // 10 blocks x 256
    __shared__ float row[DD];
    for (int i = t; i < DD; i += 256) row[i] = ptex[a * DD + i];
    __syncthreads();
    for (int dd = 0; dd < 3; ++dd) {
        int d = dd * 256 + t;
        const float* wr = wm + (size_t)d * DD;
        float acc = bm[d];
        for (int k = 0; k < DD; k += 4) {
            float4 w4 = *reinterpret_cast<const float4*>(wr + k);
            acc += row[k] * w4.x + row[k + 1] * w4.y + row[k + 2] * w4.z + row[k + 3] * w4.w;
        }
        mtext[a * DD + d] = acc;
    }
}

// ---------------- pass 1 over x: sigmoid weights + weighted sums (partials) ----------------
__global__ __launch_bounds__(256, 2)
void k_pass1(const float* __restrict__ outp, const float* __restrict__ agent,
             const int* __restrict__ layerp, float* __restrict__ num_part,
             float* __restrict__ den_part) {
    int chunk = blockIdx.x, b = blockIdx.y;  // grid (8,32)
    int tid = threadIdx.x, lane = tid & 63, wv = tid >> 6;
    __shared__ float agl[AL * DD];
    __shared__ float red[AL * DD];
    const float* ab = agent + (size_t)layerp[0] * AL * DD;
    for (int i = tid; i < AL * DD; i += 256) agl[i] = ab[i];
    __syncthreads();

    float acc[AL][12];
    float dena[AL];
    #pragma unroll
    for (int a = 0; a < AL; ++a) {
        dena[a] = 0.f;
        #pragma unroll
        for (int j = 0; j < 12; ++j) acc[a][j] = 0.f;
    }
    int n0 = chunk * 128 + wv * 32;
    for (int r = 0; r < 32; ++r) {
        int n = n0 + r;
        const float* fr = outp + ((size_t)(1 + n) * BB + b) * DD;
        float4 f0 = *reinterpret_cast<const float4*>(fr + 0 + lane * 4);
        float4 f1 = *reinterpret_cast<const float4*>(fr + 256 + lane * 4);
        float4 f2 = *reinterpret_cast<const float4*>(fr + 512 + lane * 4);
        #pragma unroll
        for (int a = 0; a < AL; ++a) {
            const float* ar = agl + a * DD + lane * 4;
            float4 a0 = *reinterpret_cast<const float4*>(ar);
            float4 a1 = *reinterpret_cast<const float4*>(ar + 256);
            float4 a2 = *reinterpret_cast<const float4*>(ar + 512);
            float p = f0.x * a0.x + f0.y * a0.y + f0.z * a0.z + f0.w * a0.w
                    + f1.x * a1.x + f1.y * a1.y + f1.z * a1.z + f1.w * a1.w
                    + f2.x * a2.x + f2.y * a2.y + f2.z * a2.z + f2.w * a2.w;
            #pragma unroll
            for (int o = 1; o < 64; o <<= 1) p += __shfl_xor(p, o);
            float w = 1.f / (1.f + __expf(-p * SCALE));
            dena[a] += w;
            acc[a][0] += w * f0.x;  acc[a][1] += w * f0.y;  acc[a][2]  += w * f0.z;  acc[a][3]  += w * f0.w;
            acc[a][4] += w * f1.x;  acc[a][5] += w * f1.y;  acc[a][6]  += w * f1.z;  acc[a][7]  += w * f1.w;
            acc[a][8] += w * f2.x;  acc[a][9] += w * f2.y;  acc[a][10] += w * f2.z;  acc[a][11] += w * f2.w;
        }
    }
    // cross-wave reduce
    for (int w2 = 0; w2 < 4; ++w2) {
        if (wv == w2) {
            #pragma unroll
            for (int a = 0; a < AL; ++a)
                #pragma unroll
                for (int j = 0; j < 3; ++j) {
                    int idx = a * DD + j * 256 + lane * 4;
                    if (w2 == 0) {
                        red[idx]     = acc[a][j*4];   red[idx + 1] = acc[a][j*4+1];
                        red[idx + 2] = acc[a][j*4+2]; red[idx + 3] = acc[a][j*4+3];
                    } else {
                        red[idx]     += acc[a][j*4];   red[idx + 1] += acc[a][j*4+1];
                        red[idx + 2] += acc[a][j*4+2]; red[idx + 3] += acc[a][j*4+3];
                    }
                }
        }
        __syncthreads();
    }
    float* np_ = num_part + ((size_t)b * 8 + chunk) * AL * DD;
    for (int i = tid; i < AL * DD; i += 256) np_[i] = red[i];
    if (lane == 0) {
        float* dp = den_part + ((size_t)(b * 8 + chunk) * 4 + wv) * AL;
        #pragma unroll
        for (int a = 0; a < AL; ++a) dp[a] = dena[a];
    }
}

// ---------------- reduce partials -> pooled_vis ----------------
__global__ void k_poolvis(const float* __restrict__ num_part, const float* __restrict__ den_part,
                          float* __restrict__ pvis) {
    int idx = blockIdx.x;  // 32*10*3
    int dch = idx % 3, a = (idx / 3) % AL, b = idx / (3 * AL);
    int d = dch * 256 + threadIdx.x;
    float num = 0.f;
    for (int c = 0; c < 8; ++c) num += num_part[((size_t)b * 8 + c) * AL * DD + a * DD + d];
    float den = 0.f;
    for (int c = 0; c < 8; ++c)
        for (int w = 0; w < 4; ++w) den += den_part[((size_t)(b * 8 + c) * 4 + w) * AL + a];
    pvis[((size_t)b * AL + a) * DD + d] = num / (den + 1e-6f);
}

// ---------------- generic C[m,n] = sum_k A[m,k]*W[n,k] (+bias) (+agent[layer][m%10]) (+mtext[m%10]) ----------------
__global__ void k_gemm_nt(const float* __restrict__ Am, const float* __restrict__ Wm,
                          const float* __restrict__ bias, const float* __restrict__ agent,
                          const int* __restrict__ layerp, const float* __restrict__ addb,
                          float* __restrict__ Cm) {
    __shared__ float As[32][33], Ws[32][33];
    int tid = threadIdx.x;
    int m0 = blockIdx.y * 32, n0 = blockIdx.x * 32;
    int ty = tid / 16, tx = tid % 16;
    float acc[2][2] = {{0.f, 0.f}, {0.f, 0.f}};
    for (int kk = 0; kk < 768; kk += 32) {
        for (int i = tid; i < 32 * 32; i += 256) {
            int r = i / 32, c = i % 32;
            int mr = m0 + r;
            As[r][c] = (mr < 320) ? Am[(size_t)mr * 768 + kk + c] : 0.f;
            Ws[r][c] = Wm[(size_t)(n0 + r) * 768 + kk + c];
        }
        __syncthreads();
        #pragma unroll
        for (int k = 0; k < 32; ++k) {
            float a0 = As[ty * 2][k], a1 = As[ty * 2 + 1][k];
            float w0 = Ws[tx * 2][k], w1 = Ws[tx * 2 + 1][k];
            acc[0][0] += a0 * w0; acc[0][1] += a0 * w1;
            acc[1][0] += a1 * w0; acc[1][1] += a1 * w1;
        }
        __syncthreads();
    }
    #pragma unroll
    for (int i = 0; i < 2; ++i) {
        int m = m0 + ty * 2 + i;
        if (m >= 320) continue;
        #pragma unroll
        for (int j = 0; j < 2; ++j) {
            int n = n0 + tx * 2 + j;
            float v = acc[i][j];
            if (bias) v += bias[n];
            if (agent) v += agent[((size_t)layerp[0] * AL + (m % AL)) * DD + n];
            if (addb) v += addb[(m % AL) * DD + n];
            Cm[(size_t)m * 768 + n] = v;
        }
    }
}

// ---------------- text attention: u = softmax(ag2 @ temb.T * scale) @ temb ----------------
__global__ void k_tattn(const float* __restrict__ ag2, const float* __restrict__ temb,
                        float* __restrict__ u) {
    int row = blockIdx.x, t = threadIdx.x;  // 320 blocks x 256
    __shared__ float q[DD];
    __shared__ float p[NC];
    __shared__ float red[256];
    for (int i = t; i < DD; i += 256) q[i] = ag2[(size_t)row * DD + i];
    __syncthreads();
    float myp = -1e30f;
    if (t < NC) {
        const float* tr = temb + (size_t)t * DD;
        float s = 0.f;
        for (int k = 0; k < DD; k += 4) {
            float4 t4 = *reinterpret_cast<const float4*>(tr + k);
            s += q[k] * t4.x + q[k + 1] * t4.y + q[k + 2] * t4.z + q[k + 3] * t4.w;
        }
        myp = s * SCALE;
    }
    red[t] = myp; __syncthreads();
    for (int o = 128; o > 0; o >>= 1) { if (t < o) red[t] = fmaxf(red[t], red[t + o]); __syncthreads(); }
    float mx = red[0]; __syncthreads();
    float e = (t < NC) ? __expf(myp - mx) : 0.f;
    red[t] = e; __syncthreads();
    for (int o = 128; o > 0; o >>= 1) { if (t < o) red[t] += red[t + o]; __syncthreads(); }
    float inv = 1.f / red[0];
    if (t < NC) p[t] = e * inv;
    __syncthreads();
    for (int dd = 0; dd < 3; ++dd) {
        int d = dd * 256 + t;
        float s = 0.f;
        for (int c = 0; c < NC; ++c) s += p[c] * temb[c * DD + d];
        u[(size_t)row * DD + d] = s;
    }
}

// ---------------- pass 2 over x: softmax over a, delta = p @ v2, fused output write ----------------
__global__ __launch_bounds__(256, 2)
void k_pass2(const float* __restrict__ outp, const float* __restrict__ ag2,
             const float* __restrict__ v2, const float* __restrict__ ascale,
             float* __restrict__ out) {
    int chunk = blockIdx.x, b = blockIdx.y;  // grid (16,32)
    int tid = threadIdx.x, lane = tid & 63, wv = tid >> 6;
    __shared__ float agl[AL * DD];
    __shared__ float vl[AL * DD];
    for (int i = tid; i < AL * DD; i += 256) {
        agl[i] = ag2[(size_t)b * AL * DD + i];
        vl[i] = v2[(size_t)b * AL * DD + i];
    }
    __syncthreads();
    float asc = ascale[0];
    int n0 = chunk * 64 + wv * 16;
    for (int r = 0; r < 16; ++r) {
        int n = n0 + r;
        const float* fr = outp + ((size_t)(1 + n) * BB + b) * DD;
        float4 f0 = *reinterpret_cast<const float4*>(fr + 0 + lane * 4);
        float4 f1 = *reinterpret_cast<const float4*>(fr + 256 + lane * 4);
        float4 f2 = *reinterpret_cast<const float4*>(fr + 512 + lane * 4);
        float s[AL];
        #pragma unroll
        for (int a = 0; a < AL; ++a) {
            const float* ar = agl + a * DD + lane * 4;
            float4 a0 = *reinterpret_cast<const float4*>(ar);
            float4 a1 = *reinterpret_cast<const float4*>(ar + 256);
            float4 a2 = *reinterpret_cast<const float4*>(ar + 512);
            float pp = f0.x * a0.x + f0.y * a0.y + f0.z * a0.z + f0.w * a0.w
                     + f1.x * a1.x + f1.y * a1.y + f1.z * a1.z + f1.w * a1.w
                     + f2.x * a2.x + f2.y * a2.y + f2.z * a2.z + f2.w * a2.w;
            #pragma unroll
            for (int o = 1; o < 64; o <<= 1) pp += __shfl_xor(pp, o);
            s[a] = pp * SCALE;
        }
        float mx = s[0];
        #pragma unroll
        for (int a = 1; a < AL; ++a) mx = fmaxf(mx, s[a]);
        float Z = 0.f;
        #pragma unroll
        for (int a = 0; a < AL; ++a) { s[a] = __expf(s[a] - mx); Z += s[a]; }
        float invZ = 1.f / Z;
        float4 d0 = {0,0,0,0}, d1 = {0,0,0,0}, d2 = {0,0,0,0};
        #pragma unroll
        for (int a = 0; a < AL; ++a) {
            float pa = s[a] * invZ;
            const float* vr = vl + a * DD + lane * 4;
            float4 v0 = *reinterpret_cast<const float4*>(vr);
            float4 v1 = *reinterpret_cast<const float4*>(vr + 256);
            float4 v2_ = *reinterpret_cast<const float4*>(vr + 512);
            d0.x += pa * v0.x;  d0.y += pa * v0.y;  d0.z += pa * v0.z;  d0.w += pa * v0.w;
            d1.x += pa * v1.x;  d1.y += pa * v1.y;  d1.z += pa * v1.z;  d1.w += pa * v1.w;
            d2.x += pa * v2_.x; d2.y += pa * v2_.y; d2.z += pa * v2_.z; d2.w += pa * v2_.w;
        }
        float* orow = out + ((size_t)(1 + n) * BB + b) * DD;
        float4 o0, o1, o2;
        o0.x = f0.x + d0.x * asc; o0.y = f0.y + d0.y * asc; o0.z = f0.z + d0.z * asc; o0.w = f0.w + d0.w * asc;
        o1.x = f1.x + d1.x * asc; o1.y = f1.y + d1.y * asc; o1.z = f1.z + d1.z * asc; o1.w = f1.w + d1.w * asc;
        o2.x = f2.x + d2.x * asc; o2.y = f2.y + d2.y * asc; o2.z = f2.z + d2.z * asc; o2.w = f2.w + d2.w * asc;
        *reinterpret_cast<float4*>(orow + 0 + lane * 4) = o0;
        *reinterpret_cast<float4*>(orow + 256 + lane * 4) = o1;
        *reinterpret_cast<float4*>(orow + 512 + lane * 4) = o2;
    }
}

extern "C" void kernel_launch(void* const* d_in, const int* in_sizes, int n_in,
                              void* d_out, int out_size, void* d_ws, size_t ws_size,
                              hipStream_t stream) {
    const float* outp   = (const float*)d_in[0];
    const float* tfeat  = (const float*)d_in[1];
    const float* agent  = (const float*)d_in[2];
    const float* ascale = (const float*)d_in[3];
    const float* w1 = (const float*)d_in[4];
    const float* b1 = (const float*)d_in[5];
    const float* w2 = (const float*)d_in[6];
    const float* b2 = (const float*)d_in[7];
    const float* wm = (const float*)d_in[8];
    const float* bm = (const float*)d_in[9];
    const float* wt = (const float*)d_in[10];
    const float* bt = (const float*)d_in[11];
    const int* layerp = (const int*)d_in[12];
    float* out = (float*)d_out;

    float* ws = (float*)d_ws;
    float* tfn      = ws;                          // 150*512
    float* temb     = tfn + NC * TD;               // 150*768
    float* wtex     = temb + NC * DD;              // 150*10
    float* ptex     = wtex + NC * AL;              // 10*768
    float* mtext    = ptex + AL * DD;              // 10*768
    float* num_part = mtext + AL * DD;             // 32*8*10*768
    float* den_part = num_part + 32 * 8 * AL * DD; // 32*8*4*10
    float* pvis     = den_part + 32 * 8 * 4 * AL;  // 32*10*768
    float* ag2      = pvis + BB * AL * DD;         // 32*10*768
    float* u        = ag2 + BB * AL * DD;          // 32*10*768
    float* v        = u + BB * AL * DD;            // 32*10*768
    float* v2      = v + BB * AL * DD;             // 32*10*768

    // cls token row: out[0] = output[0]
    hipMemcpyAsync(out, outp, (size_t)BB * DD * sizeof(float),
                   hipMemcpyDeviceToDevice, stream);

    k_textprep<<<NC, 256, 0, stream>>>(tfeat, tfn);
    k_temb<<<NC, 256, 0, stream>>>(tfn, wt, bt, temb);
    k_pass1<<<dim3(8, 32), 256, 0, stream>>>(outp, agent, layerp, num_part, den_part);
    k_wtext<<<NC * AL, 64, 0, stream>>>(temb, agent, layerp, wtex);
    k_ptext<<<30, 256, 0, stream>>>(temb, wtex, ptex);
    k_mtext<<<AL, 256, 0, stream>>>(ptex, wm, bm, mtext);
    k_poolvis<<<BB * AL * 3, 256, 0, stream>>>(num_part, den_part, pvis);
    // ag2 = pooled_vis @ wm.T + bm + agent[layer] + mtext
    k_gemm_nt<<<dim3(24, 10), 256, 0, stream>>>(pvis, wm, bm, agent, layerp, mtext, ag2);
    k_tattn<<<BB * AL, 256, 0, stream>>>(ag2, temb, u);
    // v = u @ w1.T + b1
    k_gemm_nt<<<dim3(24, 10), 256, 0, stream>>>(u, w1, b1, nullptr, layerp, nullptr, v);
    // v2 = v @ w2.T + b2   (b2 folded: softmax rows sum to 1)
    k_gemm_nt<<<dim3(24, 10), 256, 0, stream>>>(v, w2, b2, nullptr, layerp, nullptr, v2);
    k_pass2<<<dim3(16, 32), 256, 0, stream>>>(outp, ag2, v2, ascale, out);
}

// Round 2
// 725.707 us; speedup vs baseline: 1.0632x; 1.0632x over previous
//
#include <hip/hip_runtime.h>
#include <hip/hip_bf16.h>
#include <math.h>

#define BB 32
#define DD 768
#define AL 10
#define NC 150
#define CTX 77
#define TD 512
#define SCALE 0.036084391824351615f  /* 768^-0.5 */
#define CHUNKS 32
#define ROWS_PB 32   /* 1024 / CHUNKS */

// ---------------- text prep: tf = mean over ctx, then L2-normalize ----------------
__global__ void k_textprep(const float* __restrict__ tfeat, float* __restrict__ tfn) {
    int c = blockIdx.x, t = threadIdx.x;  // 150 blocks x 256
    const float* base = tfeat + (size_t)c * CTX * TD;
    float s0 = 0.f, s1 = 0.f;
    for (int j = 0; j < CTX; ++j) {
        s0 += base[j * TD + t];
        s1 += base[j * TD + t + 256];
    }
    s0 *= (1.f / CTX); s1 *= (1.f / CTX);
    __shared__ float red[256];
    red[t] = s0 * s0 + s1 * s1;
    __syncthreads();
    for (int o = 128; o > 0; o >>= 1) { if (t < o) red[t] += red[t + o]; __syncthreads(); }
    float rn = rsqrtf(red[0]);
    tfn[c * TD + t] = s0 * rn;
    tfn[c * TD + t + 256] = s1 * rn;
}

// ---------------- temb = relu(tfn @ wt.T + bt), 3 classes per block ----------------
__global__ void k_temb(const float* __restrict__ tfn, const float* __restrict__ wt,
                       const float* __restrict__ bt, float* __restrict__ temb) {
    int c0 = blockIdx.x * 3, t = threadIdx.x;  // 50 blocks x 256
    __shared__ float rows[3][TD];
    for (int i = t; i < 3 * TD; i += 256) rows[i / TD][i % TD] = tfn[(size_t)(c0 + i / TD) * TD + i % TD];
    __syncthreads();
    for (int dd = 0; dd < 3; ++dd) {
        int d = dd * 256 + t;
        const float* wr = wt + (size_t)d * TD;
        float bv = bt[d];
        float a0 = bv, a1 = bv, a2 = bv;
        for (int k = 0; k < TD; k += 4) {
            float4 w4 = *reinterpret_cast<const float4*>(wr + k);
            a0 += rows[0][k] * w4.x + rows[0][k+1] * w4.y + rows[0][k+2] * w4.z + rows[0][k+3] * w4.w;
            a1 += rows[1][k] * w4.x + rows[1][k+1] * w4.y + rows[1][k+2] * w4.z + rows[1][k+3] * w4.w;
            a2 += rows[2][k] * w4.x + rows[2][k+1] * w4.y + rows[2][k+2] * w4.z + rows[2][k+3] * w4.w;
        }
        temb[(size_t)(c0 + 0) * DD + d] = fmaxf(a0, 0.f);
        temb[(size_t)(c0 + 1) * DD + d] = fmaxf(a1, 0.f);
        temb[(size_t)(c0 + 2) * DD + d] = fmaxf(a2, 0.f);
    }
}

// ---------------- w_text[c,a] = sigmoid(scale * dot(ag[a], temb[c])) ----------------
__global__ void k_wtext(const float* __restrict__ temb, const float* __restrict__ agent,
                        const int* __restrict__ layerp, float* __restrict__ wtex) {
    int c = blockIdx.x / AL, a = blockIdx.x % AL;
    int l = threadIdx.x;  // 64
    const float* ar = agent + ((size_t)layerp[0] * AL + a) * DD;
    const float* tr = temb + (size_t)c * DD;
    float p = 0.f;
    for (int j = 0; j < 12; ++j) { int d = j * 64 + l; p += ar[d] * tr[d]; }
    #pragma unroll
    for (int o = 1; o < 64; o <<= 1) p += __shfl_xor(p, o);
    if (l == 0) wtex[c * AL + a] = 1.f / (1.f + __expf(-p * SCALE));
}

// ---------------- pooled_text[a,d] -> ptex (rows 320..329 of A330) ----------------
__global__ void k_ptext(const float* __restrict__ temb, const float* __restrict__ wtex,
                        float* __restrict__ ptex) {
    int a = blockIdx.x / 3, dch = blockIdx.x % 3;  // 30 blocks x 256
    int d = dch * 256 + threadIdx.x;
    float num = 0.f, den = 0.f;
    for (int c = 0; c < NC; ++c) {
        float wv = wtex[c * AL + a];
        num += wv * temb[(size_t)c * DD + d];
        den += wv;
    }
    ptex[(size_t)a * DD + d] = num / (den + 1e-6f);
}

// ---------------- pass 1: two-phase (weights via shfl, pooling shuffle-free) ----------------
__global__ __launch_bounds__(256, 4)
void k_pass1(const float* __restrict__ outp, const float* __restrict__ agent,
             const int* __restrict__ layerp, __hip_bfloat16* __restrict__ num_bf,
             float* __restrict__ den_part) {
    int chunk = blockIdx.x, b = blockIdx.y;  // grid (32,32)
    int tid = threadIdx.x, lane = tid & 63, wv = tid >> 6;
    __shared__ float agl[AL * DD];     // 30 KB
    __shared__ float wl[ROWS_PB * AL]; // 1.25 KB
    const float* ab = agent + (size_t)layerp[0] * AL * DD;
    for (int i = tid; i < AL * DD; i += 256) agl[i] = ab[i];
    __syncthreads();
    const float4* agl4 = reinterpret_cast<const float4*>(agl);

    // phase A: wave-per-row, sigmoid weights -> LDS
    #pragma unroll 2
    for (int r = 0; r < 8; ++r) {
        int row = wv * 8 + r;
        int n = chunk * ROWS_PB + row;
        const float* fr = outp + ((size_t)(n + 1) * BB + b) * DD;
        float4 f0 = *reinterpret_cast<const float4*>(fr + lane * 4);
        float4 f1 = *reinterpret_cast<const float4*>(fr + 256 + lane * 4);
        float4 f2 = *reinterpret_cast<const float4*>(fr + 512 + lane * 4);
        #pragma unroll
        for (int a = 0; a < AL; ++a) {
            float4 a0 = agl4[a * 192 + lane];
            float4 a1 = agl4[a * 192 + 64 + lane];
            float4 a2 = agl4[a * 192 + 128 + lane];
            float p = f0.x*a0.x + f0.y*a0.y + f0.z*a0.z + f0.w*a0.w
                    + f1.x*a1.x + f1.y*a1.y + f1.z*a1.z + f1.w*a1.w
                    + f2.x*a2.x + f2.y*a2.y + f2.z*a2.z + f2.w*a2.w;
            #pragma unroll
            for (int o = 1; o < 64; o <<= 1) p += __shfl_xor(p, o);
            float wgt = 1.f / (1.f + __expf(-p * SCALE));
            if (lane == a) wl[row * AL + a] = wgt;
        }
    }
    __syncthreads();

    // phase B: thread-per-d-column pooling, no shuffles, acc = 30 regs
    float acc0[AL], acc1[AL], acc2[AL];
    #pragma unroll
    for (int a = 0; a < AL; ++a) { acc0[a] = 0.f; acc1[a] = 0.f; acc2[a] = 0.f; }
    int nbase = chunk * ROWS_PB;
    for (int row = 0; row < ROWS_PB; ++row) {
        const float* fr = outp + ((size_t)(nbase + row + 1) * BB + b) * DD;
        float x0 = fr[tid], x1 = fr[tid + 256], x2 = fr[tid + 512];
        #pragma unroll
        for (int a = 0; a < AL; ++a) {
            float wgt = wl[row * AL + a];
            acc0[a] += wgt * x0; acc1[a] += wgt * x1; acc2[a] += wgt * x2;
        }
    }
    __hip_bfloat16* np_ = num_bf + ((size_t)b * CHUNKS + chunk) * AL * DD;
    #pragma unroll
    for (int a = 0; a < AL; ++a) {
        np_[a * DD + tid]       = __float2bfloat16(acc0[a]);
        np_[a * DD + tid + 256] = __float2bfloat16(acc1[a]);
        np_[a * DD + tid + 512] = __float2bfloat16(acc2[a]);
    }
    if (tid < AL) {
        float dn = 0.f;
        for (int row = 0; row < ROWS_PB; ++row) dn += wl[row * AL + tid];
        den_part[((size_t)b * CHUNKS + chunk) * AL + tid] = dn;
    }
}

// ---------------- reduce partials -> pooled_vis (rows 0..319 of A330) ----------------
__global__ void k_poolvis(const __hip_bfloat16* __restrict__ num_bf,
                          const float* __restrict__ den_part, float* __restrict__ pvis) {
    int idx = blockIdx.x;  // 320 = b*10+a
    int a = idx % AL, b = idx / AL;
    int t = threadIdx.x;
    float den = 0.f;
    for (int c = 0; c < CHUNKS; ++c) den += den_part[((size_t)b * CHUNKS + c) * AL + a];
    float inv = 1.f / (den + 1e-6f);
    for (int dd = 0; dd < 3; ++dd) {
        int d = dd * 256 + t;
        float num = 0.f;
        for (int c = 0; c < CHUNKS; ++c)
            num += __bfloat162float(num_bf[((size_t)b * CHUNKS + c) * AL * DD + a * DD + d]);
        pvis[((size_t)b * AL + a) * DD + d] = num * inv;
    }
}

// ---------------- generic C[m,n] = sum_k A[m,k]*W[n,k] + bias[n], m < M ----------------
__global__ void k_gemm_nt(const float* __restrict__ Am, const float* __restrict__ Wm,
                          const float* __restrict__ bias, float* __restrict__ Cm, int M) {
    __shared__ float As[32][33], Ws[32][33];
    int tid = threadIdx.x;
    int m0 = blockIdx.y * 32, n0 = blockIdx.x * 32;
    int ty = tid / 16, tx = tid % 16;
    float acc[2][2] = {{0.f, 0.f}, {0.f, 0.f}};
    for (int kk = 0; kk < DD; kk += 32) {
        for (int i = tid; i < 32 * 32; i += 256) {
            int r = i / 32, c = i % 32;
            int mr = m0 + r;
            As[r][c] = (mr < M) ? Am[(size_t)mr * DD + kk + c] : 0.f;
            Ws[r][c] = Wm[(size_t)(n0 + r) * DD + kk + c];
        }
        __syncthreads();
        #pragma unroll
        for (int k = 0; k < 32; ++k) {
            float a0 = As[ty * 2][k], a1 = As[ty * 2 + 1][k];
            float w0 = Ws[tx * 2][k], w1 = Ws[tx * 2 + 1][k];
            acc[0][0] += a0 * w0; acc[0][1] += a0 * w1;
            acc[1][0] += a1 * w0; acc[1][1] += a1 * w1;
        }
        __syncthreads();
    }
    #pragma unroll
    for (int i = 0; i < 2; ++i) {
        int m = m0 + ty * 2 + i;
        if (m >= M) continue;
        #pragma unroll
        for (int j = 0; j < 2; ++j) {
            int n = n0 + tx * 2 + j;
            Cm[(size_t)m * DD + n] = acc[i][j] + bias[n];
        }
    }
}

// ---------------- ag2 = C[m] + C[320 + m%10] + agent[layer][m%10] ----------------
__global__ void k_add_ag2(const float* __restrict__ C330, const float* __restrict__ agent,
                          const int* __restrict__ layerp, float* __restrict__ ag2) {
    int m = blockIdx.x, a = m % AL, t = threadIdx.x;  // 320 blocks x 256
    const float* arow = agent + ((size_t)layerp[0] * AL + a) * DD;
    for (int dd = 0; dd < 3; ++dd) {
        int d = dd * 256 + t;
        ag2[(size_t)m * DD + d] = C330[(size_t)m * DD + d] + C330[(size_t)(320 + a) * DD + d] + arow[d];
    }
}

// ---------------- text attention, 5 agents per block: u = softmax(ag2@temb.T*scale)@temb ----------------
__global__ void k_tattn(const float* __restrict__ ag2, const float* __restrict__ temb,
                        float* __restrict__ u) {
    int h = blockIdx.x, b = blockIdx.y;  // grid (2,32) x 256
    int t = threadIdx.x, lane = t & 63, wv = t >> 6;
    __shared__ float q[5 * DD];     // 15 KB
    __shared__ float S[5][152];
    const float* qb = ag2 + ((size_t)b * AL + h * 5) * DD;
    for (int i = t; i < 5 * DD; i += 256) q[i] = qb[i];
    __syncthreads();
    if (t < NC) {
        const float* tr = temb + (size_t)t * DD;
        float s0 = 0.f, s1 = 0.f, s2 = 0.f, s3 = 0.f, s4 = 0.f;
        for (int k = 0; k < DD; k += 4) {
            float4 t4 = *reinterpret_cast<const float4*>(tr + k);
            s0 += q[0*DD+k]*t4.x + q[0*DD+k+1]*t4.y + q[0*DD+k+2]*t4.z + q[0*DD+k+3]*t4.w;
            s1 += q[1*DD+k]*t4.x + q[1*DD+k+1]*t4.y + q[1*DD+k+2]*t4.z + q[1*DD+k+3]*t4.w;
            s2 += q[2*DD+k]*t4.x + q[2*DD+k+1]*t4.y + q[2*DD+k+2]*t4.z + q[2*DD+k+3]*t4.w;
            s3 += q[3*DD+k]*t4.x + q[3*DD+k+1]*t4.y + q[3*DD+k+2]*t4.z + q[3*DD+k+3]*t4.w;
            s4 += q[4*DD+k]*t4.x + q[4*DD+k+1]*t4.y + q[4*DD+k+2]*t4.z + q[4*DD+k+3]*t4.w;
        }
        S[0][t] = s0 * SCALE; S[1][t] = s1 * SCALE; S[2][t] = s2 * SCALE;
        S[3][t] = s3 * SCALE; S[4][t] = s4 * SCALE;
    }
    __syncthreads();
    // softmax rows: wave wv does row wv; wave 0 also row 4
    for (int j = wv; j < 5; j += 4) {
        float v0 = S[j][lane];
        float v1 = S[j][lane + 64];
        float v2 = (lane < NC - 128) ? S[j][lane + 128] : -1e30f;
        float m = fmaxf(fmaxf(v0, v1), v2);
        #pragma unroll
        for (int o = 1; o < 64; o <<= 1) m = fmaxf(m, __shfl_xor(m, o));
        float e0 = __expf(v0 - m), e1 = __expf(v1 - m);
        float e2 = (lane < NC - 128) ? __expf(v2 - m) : 0.f;
        float z = e0 + e1 + e2;
        #pragma unroll
        for (int o = 1; o < 64; o <<= 1) z += __shfl_xor(z, o);
        float inv = 1.f / z;
        S[j][lane] = e0 * inv; S[j][lane + 64] = e1 * inv;
        if (lane < NC - 128) S[j][lane + 128] = e2 * inv;
    }
    __syncthreads();
    float u0[5], u1[5], u2[5];
    #pragma unroll
    for (int j = 0; j < 5; ++j) { u0[j] = 0.f; u1[j] = 0.f; u2[j] = 0.f; }
    for (int c = 0; c < NC; ++c) {
        const float* tr = temb + (size_t)c * DD;
        float t0 = tr[t], t1 = tr[t + 256], t2 = tr[t + 512];
        #pragma unroll
        for (int j = 0; j < 5; ++j) {
            float pj = S[j][c];
            u0[j] += pj * t0; u1[j] += pj * t1; u2[j] += pj * t2;
        }
    }
    #pragma unroll
    for (int j = 0; j < 5; ++j) {
        float* ur = u + ((size_t)b * AL + h * 5 + j) * DD;
        ur[t] = u0[j]; ur[t + 256] = u1[j]; ur[t + 512] = u2[j];
    }
}

// ---------------- pass 2: two-phase (softmax via shfl, AV shuffle-free, fused residual) ----------------
__global__ __launch_bounds__(256, 4)
void k_pass2(const float* __restrict__ outp, const float* __restrict__ ag2,
             const float* __restrict__ v2, const float* __restrict__ ascale,
             float* __restrict__ out) {
    int chunk = blockIdx.x, b = blockIdx.y;  // grid (32,32)
    int tid = threadIdx.x, lane = tid & 63, wv = tid >> 6;
    __shared__ float agl[AL * DD];      // 30 KB
    __shared__ float Pl[ROWS_PB * AL];  // 1.25 KB
    // v2 fragments straight into registers (30 regs), issued early
    float vr0[AL], vr1[AL], vr2[AL];
    #pragma unroll
    for (int a = 0; a < AL; ++a) {
        const float* vrow = v2 + ((size_t)b * AL + a) * DD;
        vr0[a] = vrow[tid]; vr1[a] = vrow[tid + 256]; vr2[a] = vrow[tid + 512];
    }
    const float* ab = ag2 + (size_t)b * AL * DD;
    for (int i = tid; i < AL * DD; i += 256) agl[i] = ab[i];
    __syncthreads();
    const float4* agl4 = reinterpret_cast<const float4*>(agl);

    // phase A: wave-per-row softmax probs -> LDS
    #pragma unroll 2
    for (int r = 0; r < 8; ++r) {
        int row = wv * 8 + r;
        int n = chunk * ROWS_PB + row;
        const float* fr = outp + ((size_t)(n + 1) * BB + b) * DD;
        float4 f0 = *reinterpret_cast<const float4*>(fr + lane * 4);
        float4 f1 = *reinterpret_cast<const float4*>(fr + 256 + lane * 4);
        float4 f2 = *reinterpret_cast<const float4*>(fr + 512 + lane * 4);
        float s[AL];
        #pragma unroll
        for (int a = 0; a < AL; ++a) {
            float4 a0 = agl4[a * 192 + lane];
            float4 a1 = agl4[a * 192 + 64 + lane];
            float4 a2 = agl4[a * 192 + 128 + lane];
            float p = f0.x*a0.x + f0.y*a0.y + f0.z*a0.z + f0.w*a0.w
                    + f1.x*a1.x + f1.y*a1.y + f1.z*a1.z + f1.w*a1.w
                    + f2.x*a2.x + f2.y*a2.y + f2.z*a2.z + f2.w*a2.w;
            #pragma unroll
            for (int o = 1; o < 64; o <<= 1) p += __shfl_xor(p, o);
            s[a] = p * SCALE;
        }
        float mx = s[0];
        #pragma unroll
        for (int a = 1; a < AL; ++a) mx = fmaxf(mx, s[a]);
        float e[AL]; float Z = 0.f;
        #pragma unroll
        for (int a = 0; a < AL; ++a) { e[a] = __expf(s[a] - mx); Z += e[a]; }
        float invZ = 1.f / Z;
        #pragma unroll
        for (int a = 0; a < AL; ++a) {
            if (lane == a) Pl[row * AL + a] = e[a] * invZ;
        }
    }
    __syncthreads();

    // phase B: thread-per-d-column AV + residual, no shuffles
    float asc = ascale[0];
    int nbase = chunk * ROWS_PB;
    for (int row = 0; row < ROWS_PB; ++row) {
        const float* fr = outp + ((size_t)(nbase + row + 1) * BB + b) * DD;
        float x0 = fr[tid], x1 = fr[tid + 256], x2 = fr[tid + 512];
        float d0 = 0.f, d1 = 0.f, d2 = 0.f;
        #pragma unroll
        for (int a = 0; a < AL; ++a) {
            float pa = Pl[row * AL + a];
            d0 += pa * vr0[a]; d1 += pa * vr1[a]; d2 += pa * vr2[a];
        }
        float* orow = out + ((size_t)(nbase + row + 1) * BB + b) * DD;
        orow[tid]       = x0 + d0 * asc;
        orow[tid + 256] = x1 + d1 * asc;
        orow[tid + 512] = x2 + d2 * asc;
    }
}

extern "C" void kernel_launch(void* const* d_in, const int* in_sizes, int n_in,
                              void* d_out, int out_size, void* d_ws, size_t ws_size,
                              hipStream_t stream) {
    const float* outp   = (const float*)d_in[0];
    const float* tfeat  = (const float*)d_in[1];
    const float* agent  = (const float*)d_in[2];
    const float* ascale = (const float*)d_in[3];
    const float* w1 = (const float*)d_in[4];
    const float* b1 = (const float*)d_in[5];
    const float* w2 = (const float*)d_in[6];
    const float* b2 = (const float*)d_in[7];
    const float* wm = (const float*)d_in[8];
    const float* bm = (const float*)d_in[9];
    const float* wt = (const float*)d_in[10];
    const float* bt = (const float*)d_in[11];
    const int* layerp = (const int*)d_in[12];
    float* out = (float*)d_out;

    float* ws = (float*)d_ws;
    float* tfn   = ws;                    // 150*512 = 76800
    float* temb  = tfn + NC * TD;         // 150*768 = 115200
    float* wtex  = temb + NC * DD;        // 1500
    float* A330  = wtex + NC * AL;        // 330*768 (pvis rows 0..319, ptex rows 320..329)
    float* C330  = A330 + 330 * DD;       // 330*768
    float* ag2   = C330 + 330 * DD;       // 320*768
    float* u     = ag2 + BB * AL * DD;    // 320*768
    float* v     = u + BB * AL * DD;      // 320*768
    float* v2    = v + BB * AL * DD;      // 320*768
    float* den_part = v2 + BB * AL * DD;  // 32*32*10
    __hip_bfloat16* num_bf = (__hip_bfloat16*)(den_part + BB * CHUNKS * AL); // 32*32*7680 bf16

    float* pvis = A330;
    float* ptex = A330 + 320 * DD;

    // cls token row: out[0] = output[0]
    hipMemcpyAsync(out, outp, (size_t)BB * DD * sizeof(float),
                   hipMemcpyDeviceToDevice, stream);

    k_pass1<<<dim3(CHUNKS, BB), 256, 0, stream>>>(outp, agent, layerp, num_bf, den_part);
    k_textprep<<<NC, 256, 0, stream>>>(tfeat, tfn);
    k_temb<<<NC / 3, 256, 0, stream>>>(tfn, wt, bt, temb);
    k_wtext<<<NC * AL, 64, 0, stream>>>(temb, agent, layerp, wtex);
    k_ptext<<<30, 256, 0, stream>>>(temb, wtex, ptex);
    k_poolvis<<<BB * AL, 256, 0, stream>>>(num_bf, den_part, pvis);
    // C330 = A330 @ wm.T + bm   (rows 0..319: masked_vis ; rows 320..329: masked_text)
    k_gemm_nt<<<dim3(24, 11), 256, 0, stream>>>(A330, wm, bm, C330, 330);
    k_add_ag2<<<BB * AL, 256, 0, stream>>>(C330, agent, layerp, ag2);
    k_tattn<<<dim3(2, BB), 256, 0, stream>>>(ag2, temb, u);
    // v = u @ w1.T + b1
    k_gemm_nt<<<dim3(24, 10), 256, 0, stream>>>(u, w1, b1, v, 320);
    // v2 = v @ w2.T + b2   (b2 folded: softmax rows sum to 1)
    k_gemm_nt<<<dim3(24, 10), 256, 0, stream>>>(v, w2, b2, v2, 320);
    k_pass2<<<dim3(CHUNKS, BB), 256, 0, stream>>>(outp, ag2, v2, ascale, out);
}

// Round 3
// 478.906 us; speedup vs baseline: 1.6110x; 1.5153x over previous
//
#include <hip/hip_runtime.h>
#include <hip/hip_bf16.h>
#include <math.h>

#define BB 32
#define DD 768
#define AL 10
#define NC 150
#define CTX 77
#define TD 512
#define SCALE 0.036084391824351615f  /* 768^-0.5 */
#define CHUNKS 32
#define ROWS_PB 32   /* rows per block = 1024 / CHUNKS */

// ---------------- text prep stage 1: partial ctx sums ----------------
__global__ void k_tp1(const float* __restrict__ tfeat, float* __restrict__ tpart) {
    int c = blockIdx.x, qq = blockIdx.y;  // (150,4)
    int t = threadIdx.x;
    int j0 = qq * 20, j1 = (qq == 3) ? CTX : j0 + 20;
    const float* base = tfeat + (size_t)c * CTX * TD;
    float s0 = 0.f, s1 = 0.f;
    for (int j = j0; j < j1; ++j) {
        s0 += base[j * TD + t];
        s1 += base[j * TD + t + 256];
    }
    tpart[((size_t)c * 4 + qq) * TD + t] = s0;
    tpart[((size_t)c * 4 + qq) * TD + t + 256] = s1;
}

// ---------------- text prep stage 2: combine, mean, L2-normalize ----------------
__global__ void k_tp2(const float* __restrict__ tpart, float* __restrict__ tfn) {
    int c = blockIdx.x, t = threadIdx.x;  // 150 x 256
    float s0 = 0.f, s1 = 0.f;
    for (int q = 0; q < 4; ++q) {
        s0 += tpart[((size_t)c * 4 + q) * TD + t];
        s1 += tpart[((size_t)c * 4 + q) * TD + t + 256];
    }
    s0 *= (1.f / CTX); s1 *= (1.f / CTX);
    __shared__ float red[256];
    red[t] = s0 * s0 + s1 * s1;
    __syncthreads();
    for (int o = 128; o > 0; o >>= 1) { if (t < o) red[t] += red[t + o]; __syncthreads(); }
    float rn = rsqrtf(red[0]);
    tfn[c * TD + t] = s0 * rn;
    tfn[c * TD + t + 256] = s1 * rn;
}

// ---------------- temb = relu(tfn @ wt.T + bt) : grid (150, 3) ----------------
__global__ void k_temb(const float* __restrict__ tfn, const float* __restrict__ wt,
                       const float* __restrict__ bt, float* __restrict__ temb) {
    int c = blockIdx.x, dch = blockIdx.y;
    int t = threadIdx.x;
    __shared__ float row[TD];
    row[t] = tfn[(size_t)c * TD + t];
    row[t + 256] = tfn[(size_t)c * TD + t + 256];
    __syncthreads();
    int d = dch * 256 + t;
    const float* wr = wt + (size_t)d * TD;
    float acc = bt[d];
    for (int k = 0; k < TD; k += 4) {
        float4 w4 = *reinterpret_cast<const float4*>(wr + k);
        acc += row[k] * w4.x + row[k + 1] * w4.y + row[k + 2] * w4.z + row[k + 3] * w4.w;
    }
    temb[(size_t)c * DD + d] = fmaxf(acc, 0.f);
}

// ---------------- w_text[c,a] = sigmoid(scale * dot(ag[a], temb[c])) ----------------
__global__ void k_wtext(const float* __restrict__ temb, const float* __restrict__ agent,
                        const int* __restrict__ layerp, float* __restrict__ wtex) {
    int c = blockIdx.x / AL, a = blockIdx.x % AL;
    int l = threadIdx.x;  // 64
    const float* ar = agent + ((size_t)layerp[0] * AL + a) * DD;
    const float* tr = temb + (size_t)c * DD;
    float p = 0.f;
    for (int j = 0; j < 12; ++j) { int d = j * 64 + l; p += ar[d] * tr[d]; }
    #pragma unroll
    for (int o = 1; o < 64; o <<= 1) p += __shfl_xor(p, o);
    if (l == 0) wtex[c * AL + a] = 1.f / (1.f + __expf(-p * SCALE));
}

// ---------------- pooled_text -> ptex ----------------
__global__ void k_ptext(const float* __restrict__ temb, const float* __restrict__ wtex,
                        float* __restrict__ ptex) {
    int a = blockIdx.x / 3, dch = blockIdx.x % 3;  // 30 x 256
    int d = dch * 256 + threadIdx.x;
    float num = 0.f, den = 0.f;
    for (int c = 0; c < NC; ++c) {
        float wv = wtex[c * AL + a];
        num += wv * temb[(size_t)c * DD + d];
        den += wv;
    }
    ptex[(size_t)a * DD + d] = num / (den + 1e-6f);
}

// ---------------- B10[a,d] = ptex[a]@wm[d] + bm[d] + agent[layer][a][d] : grid (10,3) ----------------
__global__ void k_mtextB10(const float* __restrict__ ptex, const float* __restrict__ wm,
                           const float* __restrict__ bm, const float* __restrict__ agent,
                           const int* __restrict__ layerp, float* __restrict__ B10) {
    int a = blockIdx.x, dch = blockIdx.y;
    int t = threadIdx.x;
    __shared__ float row[DD];
    for (int i = t; i < DD; i += 256) row[i] = ptex[(size_t)a * DD + i];
    __syncthreads();
    int d = dch * 256 + t;
    const float* wr = wm + (size_t)d * DD;
    float acc = 0.f;
    for (int k = 0; k < DD; k += 4) {
        float4 w4 = *reinterpret_cast<const float4*>(wr + k);
        acc += row[k] * w4.x + row[k + 1] * w4.y + row[k + 2] * w4.z + row[k + 3] * w4.w;
    }
    B10[(size_t)a * DD + d] = acc + bm[d] + agent[((size_t)layerp[0] * AL + a) * DD + d];
}

// ---------------- pass 1: single x read, LDS row-group staging ----------------
__global__ __launch_bounds__(256, 2)
void k_pass1(const float* __restrict__ outp, const float* __restrict__ agent,
             const int* __restrict__ layerp, __hip_bfloat16* __restrict__ num_bf,
             float* __restrict__ den_part) {
    int chunk = blockIdx.x, b = blockIdx.y;  // (32,32)
    int tid = threadIdx.x, lane = tid & 63, w = tid >> 6;
    __shared__ float agl[AL * DD];       // 30 KB
    __shared__ float xs[8][DD];          // 24 KB
    __shared__ float wl[ROWS_PB][AL];    // 1.25 KB
    const float* ab = agent + (size_t)layerp[0] * AL * DD;
    for (int i = tid; i < AL * DD; i += 256) agl[i] = ab[i];
    float acc0[AL], acc1[AL], acc2[AL];
    #pragma unroll
    for (int a = 0; a < AL; ++a) { acc0[a] = 0.f; acc1[a] = 0.f; acc2[a] = 0.f; }
    __syncthreads();
    for (int g = 0; g < 4; ++g) {
        int la = w * 2, lb = la + 1;
        int ga = g * 8 + la, gb = ga + 1;
        // load this wave's 2 rows into regs (strided float4 slices) and stage to LDS
        const float* pA = outp + ((size_t)(1 + chunk * ROWS_PB + ga) * BB + b) * DD + lane * 4;
        const float* pB = pA + (size_t)BB * DD;
        float4 xa0 = *(const float4*)(pA);
        float4 xa1 = *(const float4*)(pA + 256);
        float4 xa2 = *(const float4*)(pA + 512);
        float4 xb0 = *(const float4*)(pB);
        float4 xb1 = *(const float4*)(pB + 256);
        float4 xb2 = *(const float4*)(pB + 512);
        *(float4*)(&xs[la][lane * 4])       = xa0;
        *(float4*)(&xs[la][lane * 4 + 256]) = xa1;
        *(float4*)(&xs[la][lane * 4 + 512]) = xa2;
        *(float4*)(&xs[lb][lane * 4])       = xb0;
        *(float4*)(&xs[lb][lane * 4 + 256]) = xb1;
        *(float4*)(&xs[lb][lane * 4 + 512]) = xb2;
        // phase A: sigmoid weights from register slices + LDS agent fragments
        #pragma unroll
        for (int a = 0; a < AL; ++a) {
            const float* agc = agl + a * DD + lane * 4;
            float4 c0 = *(const float4*)(agc);
            float4 c1 = *(const float4*)(agc + 256);
            float4 c2 = *(const float4*)(agc + 512);
            float pa = xa0.x*c0.x + xa0.y*c0.y + xa0.z*c0.z + xa0.w*c0.w
                     + xa1.x*c1.x + xa1.y*c1.y + xa1.z*c1.z + xa1.w*c1.w
                     + xa2.x*c2.x + xa2.y*c2.y + xa2.z*c2.z + xa2.w*c2.w;
            float pb = xb0.x*c0.x + xb0.y*c0.y + xb0.z*c0.z + xb0.w*c0.w
                     + xb1.x*c1.x + xb1.y*c1.y + xb1.z*c1.z + xb1.w*c1.w
                     + xb2.x*c2.x + xb2.y*c2.y + xb2.z*c2.z + xb2.w*c2.w;
            #pragma unroll
            for (int o = 1; o < 64; o <<= 1) { pa += __shfl_xor(pa, o); pb += __shfl_xor(pb, o); }
            if (lane == a) {
                wl[ga][a] = 1.f / (1.f + __expf(-pa * SCALE));
                wl[gb][a] = 1.f / (1.f + __expf(-pb * SCALE));
            }
        }
        __syncthreads();
        // phase B: column-wise pooling from LDS
        #pragma unroll
        for (int row = 0; row < 8; ++row) {
            float x0 = xs[row][tid], x1 = xs[row][tid + 256], x2 = xs[row][tid + 512];
            int rw = g * 8 + row;
            #pragma unroll
            for (int a = 0; a < AL; ++a) {
                float wg = wl[rw][a];
                acc0[a] += wg * x0; acc1[a] += wg * x1; acc2[a] += wg * x2;
            }
        }
        __syncthreads();
    }
    __hip_bfloat16* np_ = num_bf + ((size_t)b * CHUNKS + chunk) * AL * DD;
    #pragma unroll
    for (int a = 0; a < AL; ++a) {
        np_[a * DD + tid]       = __float2bfloat16(acc0[a]);
        np_[a * DD + tid + 256] = __float2bfloat16(acc1[a]);
        np_[a * DD + tid + 512] = __float2bfloat16(acc2[a]);
    }
    if (tid < AL) {
        float dn = 0.f;
        for (int rw = 0; rw < ROWS_PB; ++rw) dn += wl[rw][tid];
        den_part[((size_t)b * CHUNKS + chunk) * AL + tid] = dn;
    }
}

// ---------------- reduce partials -> pooled_vis ----------------
__global__ void k_poolvis(const __hip_bfloat16* __restrict__ num_bf,
                          const float* __restrict__ den_part, float* __restrict__ pvis) {
    int idx = blockIdx.x;  // 320 = b*10+a
    int a = idx % AL, b = idx / AL;
    int t = threadIdx.x;
    float den = 0.f;
    for (int c = 0; c < CHUNKS; ++c) den += den_part[((size_t)b * CHUNKS + c) * AL + a];
    float inv = 1.f / (den + 1e-6f);
    for (int dd = 0; dd < 3; ++dd) {
        int d = dd * 256 + t;
        float num = 0.f;
        for (int c = 0; c < CHUNKS; ++c)
            num += __bfloat162float(num_bf[((size_t)b * CHUNKS + c) * AL * DD + a * DD + d]);
        pvis[((size_t)b * AL + a) * DD + d] = num * inv;
    }
}

// ---------------- split-K GEMM: part[ks][m][n] = A[m,k0:k0+192] @ W[n,k0:k0+192]^T ----------------
__global__ __launch_bounds__(256)
void k_gemmsk(const float* __restrict__ A, const float* __restrict__ W,
              float* __restrict__ part) {
    // grid (12, 5, 4): n-tile 64, m-tile 64, k-split 192
    int n0 = blockIdx.x * 64, m0 = blockIdx.y * 64, k0 = blockIdx.z * 192;
    int tid = threadIdx.x;
    int tx = tid % 16, ty = tid / 16;
    __shared__ float As[64][36];
    __shared__ float Ws[64][36];
    float acc[4][4] = {};
    for (int kk = 0; kk < 192; kk += 32) {
        #pragma unroll
        for (int s = 0; s < 2; ++s) {
            int i = s * 256 + tid;              // 0..511
            int r = i >> 3, c4 = (i & 7) * 4;   // 8 float4 per row of 32 k
            float4 av = *reinterpret_cast<const float4*>(A + (size_t)(m0 + r) * DD + k0 + kk + c4);
            float4 wv = *reinterpret_cast<const float4*>(W + (size_t)(n0 + r) * DD + k0 + kk + c4);
            *reinterpret_cast<float4*>(&As[r][c4]) = av;
            *reinterpret_cast<float4*>(&Ws[r][c4]) = wv;
        }
        __syncthreads();
        #pragma unroll
        for (int k4 = 0; k4 < 32; k4 += 4) {
            float4 a[4], wv[4];
            #pragma unroll
            for (int i = 0; i < 4; ++i) a[i] = *reinterpret_cast<const float4*>(&As[ty * 4 + i][k4]);
            #pragma unroll
            for (int j = 0; j < 4; ++j) wv[j] = *reinterpret_cast<const float4*>(&Ws[tx * 4 + j][k4]);
            #pragma unroll
            for (int i = 0; i < 4; ++i)
                #pragma unroll
                for (int j = 0; j < 4; ++j)
                    acc[i][j] += a[i].x * wv[j].x + a[i].y * wv[j].y
                               + a[i].z * wv[j].z + a[i].w * wv[j].w;
        }
        __syncthreads();
    }
    float* pb = part + (size_t)blockIdx.z * 320 * DD;
    #pragma unroll
    for (int i = 0; i < 4; ++i) {
        int m = m0 + ty * 4 + i;
        #pragma unroll
        for (int j = 0; j < 4; ++j)
            pb[(size_t)m * DD + n0 + tx * 4 + j] = acc[i][j];
    }
}

// ---------------- reduce split-K partials + bias (+per-agent row bias) ----------------
__global__ void k_gemmred(const float* __restrict__ part, const float* __restrict__ bias,
                          const float* __restrict__ brow, float* __restrict__ dst) {
    int m = blockIdx.x, t = threadIdx.x;  // 320 x 256
    int a = m % AL;
    for (int dd = 0; dd < 3; ++dd) {
        int d = dd * 256 + t;
        float v = part[(size_t)m * DD + d]
                + part[(size_t)320 * DD + (size_t)m * DD + d]
                + part[(size_t)2 * 320 * DD + (size_t)m * DD + d]
                + part[(size_t)3 * 320 * DD + (size_t)m * DD + d];
        v += bias[d];
        if (brow) v += brow[(size_t)a * DD + d];
        dst[(size_t)m * DD + d] = v;
    }
}

// ---------------- text attention, 1 agent per block: grid (10, 32) ----------------
__global__ void k_tattn(const float* __restrict__ ag2, const float* __restrict__ temb,
                        float* __restrict__ u) {
    int a = blockIdx.x, b = blockIdx.y;
    int t = threadIdx.x;
    __shared__ float q[DD];
    __shared__ float p[NC];
    __shared__ float red[256];
    const float* qb = ag2 + ((size_t)b * AL + a) * DD;
    for (int i = t; i < DD; i += 256) q[i] = qb[i];
    __syncthreads();
    float myp = -1e30f;
    if (t < NC) {
        const float* tr = temb + (size_t)t * DD;
        float s = 0.f;
        for (int k = 0; k < DD; k += 4) {
            float4 t4 = *reinterpret_cast<const float4*>(tr + k);
            s += q[k] * t4.x + q[k + 1] * t4.y + q[k + 2] * t4.z + q[k + 3] * t4.w;
        }
        myp = s * SCALE;
    }
    red[t] = myp; __syncthreads();
    for (int o = 128; o > 0; o >>= 1) { if (t < o) red[t] = fmaxf(red[t], red[t + o]); __syncthreads(); }
    float mx = red[0]; __syncthreads();
    float e = (t < NC) ? __expf(myp - mx) : 0.f;
    red[t] = e; __syncthreads();
    for (int o = 128; o > 0; o >>= 1) { if (t < o) red[t] += red[t + o]; __syncthreads(); }
    float inv = 1.f / red[0];
    if (t < NC) p[t] = e * inv;
    __syncthreads();
    float u0 = 0.f, u1 = 0.f, u2 = 0.f;
    for (int c = 0; c < NC; ++c) {
        const float* tr = temb + (size_t)c * DD;
        float pc = p[c];
        u0 += pc * tr[t]; u1 += pc * tr[t + 256]; u2 += pc * tr[t + 512];
    }
    float* ur = u + ((size_t)b * AL + a) * DD;
    ur[t] = u0; ur[t + 256] = u1; ur[t + 512] = u2;
}

// ---------------- pass 2: single x read, fused softmax + AV + residual ----------------
__global__ __launch_bounds__(256, 2)
void k_pass2(const float* __restrict__ outp, const float* __restrict__ ag2,
             const float* __restrict__ v2, const float* __restrict__ ascale,
             float* __restrict__ out) {
    int chunk = blockIdx.x, b = blockIdx.y;  // (32,32)
    int tid = threadIdx.x, lane = tid & 63, w = tid >> 6;
    __shared__ float agl[AL * DD];   // 30 KB
    __shared__ float xs[8][DD];      // 24 KB
    __shared__ float pl[8][AL];
    float vr0[AL], vr1[AL], vr2[AL];
    #pragma unroll
    for (int a = 0; a < AL; ++a) {
        const float* vrow = v2 + ((size_t)b * AL + a) * DD;
        vr0[a] = vrow[tid]; vr1[a] = vrow[tid + 256]; vr2[a] = vrow[tid + 512];
    }
    const float* ab = ag2 + (size_t)b * AL * DD;
    for (int i = tid; i < AL * DD; i += 256) agl[i] = ab[i];
    float asc = ascale[0];
    __syncthreads();
    for (int g = 0; g < 4; ++g) {
        int la = w * 2, lb = la + 1;
        int ga = g * 8 + la, gb = ga + 1;
        const float* pA = outp + ((size_t)(1 + chunk * ROWS_PB + ga) * BB + b) * DD + lane * 4;
        const float* pB = pA + (size_t)BB * DD;
        float4 xa0 = *(const float4*)(pA);
        float4 xa1 = *(const float4*)(pA + 256);
        float4 xa2 = *(const float4*)(pA + 512);
        float4 xb0 = *(const float4*)(pB);
        float4 xb1 = *(const float4*)(pB + 256);
        float4 xb2 = *(const float4*)(pB + 512);
        *(float4*)(&xs[la][lane * 4])       = xa0;
        *(float4*)(&xs[la][lane * 4 + 256]) = xa1;
        *(float4*)(&xs[la][lane * 4 + 512]) = xa2;
        *(float4*)(&xs[lb][lane * 4])       = xb0;
        *(float4*)(&xs[lb][lane * 4 + 256]) = xb1;
        *(float4*)(&xs[lb][lane * 4 + 512]) = xb2;
        float sA[AL], sB[AL];
        #pragma unroll
        for (int a = 0; a < AL; ++a) {
            const float* agc = agl + a * DD + lane * 4;
            float4 c0 = *(const float4*)(agc);
            float4 c1 = *(const float4*)(agc + 256);
            float4 c2 = *(const float4*)(agc + 512);
            float pa = xa0.x*c0.x + xa0.y*c0.y + xa0.z*c0.z + xa0.w*c0.w
                     + xa1.x*c1.x + xa1.y*c1.y + xa1.z*c1.z + xa1.w*c1.w
                     + xa2.x*c2.x + xa2.y*c2.y + xa2.z*c2.z + xa2.w*c2.w;
            float pb = xb0.x*c0.x + xb0.y*c0.y + xb0.z*c0.z + xb0.w*c0.w
                     + xb1.x*c1.x + xb1.y*c1.y + xb1.z*c1.z + xb1.w*c1.w
                     + xb2.x*c2.x + xb2.y*c2.y + xb2.z*c2.z + xb2.w*c2.w;
            #pragma unroll
            for (int o = 1; o < 64; o <<= 1) { pa += __shfl_xor(pa, o); pb += __shfl_xor(pb, o); }
            sA[a] = pa * SCALE; sB[a] = pb * SCALE;
        }
        // softmax in registers (all lanes redundantly)
        float mA = sA[0], mB = sB[0];
        #pragma unroll
        for (int a = 1; a < AL; ++a) { mA = fmaxf(mA, sA[a]); mB = fmaxf(mB, sB[a]); }
        float ZA = 0.f, ZB = 0.f;
        #pragma unroll
        for (int a = 0; a < AL; ++a) {
            sA[a] = __expf(sA[a] - mA); ZA += sA[a];
            sB[a] = __expf(sB[a] - mB); ZB += sB[a];
        }
        float iA = asc / ZA, iB = asc / ZB;
        #pragma unroll
        for (int a = 0; a < AL; ++a) {
            if (lane == a) { pl[la][a] = sA[a] * iA; pl[lb][a] = sB[a] * iB; }
        }
        __syncthreads();
        #pragma unroll
        for (int row = 0; row < 8; ++row) {
            float x0 = xs[row][tid], x1 = xs[row][tid + 256], x2 = xs[row][tid + 512];
            float d0 = 0.f, d1 = 0.f, d2 = 0.f;
            #pragma unroll
            for (int a = 0; a < AL; ++a) {
                float pa = pl[row][a];
                d0 += pa * vr0[a]; d1 += pa * vr1[a]; d2 += pa * vr2[a];
            }
            float* orow = out + ((size_t)(1 + chunk * ROWS_PB + g * 8 + row) * BB + b) * DD;
            orow[tid]       = x0 + d0;
            orow[tid + 256] = x1 + d1;
            orow[tid + 512] = x2 + d2;
        }
        __syncthreads();
    }
}

extern "C" void kernel_launch(void* const* d_in, const int* in_sizes, int n_in,
                              void* d_out, int out_size, void* d_ws, size_t ws_size,
                              hipStream_t stream) {
    const float* outp   = (const float*)d_in[0];
    const float* tfeat  = (const float*)d_in[1];
    const float* agent  = (const float*)d_in[2];
    const float* ascale = (const float*)d_in[3];
    const float* w1 = (const float*)d_in[4];
    const float* b1 = (const float*)d_in[5];
    const float* w2 = (const float*)d_in[6];
    const float* b2 = (const float*)d_in[7];
    const float* wm = (const float*)d_in[8];
    const float* bm = (const float*)d_in[9];
    const float* wt = (const float*)d_in[10];
    const float* bt = (const float*)d_in[11];
    const int* layerp = (const int*)d_in[12];
    float* out = (float*)d_out;

    float* ws = (float*)d_ws;
    float* tfn   = ws;                    // 76800
    float* temb  = tfn + NC * TD;         // 115200
    float* wtex  = temb + NC * DD;        // 1500
    float* ptex  = wtex + NC * AL;        // 7680
    float* B10   = ptex + AL * DD;        // 7680
    float* pvis  = B10 + AL * DD;         // 245760
    float* ag2   = pvis + BB * AL * DD;   // 245760
    float* u     = ag2 + BB * AL * DD;    // 245760
    float* v     = u + BB * AL * DD;      // 245760
    float* v2    = v + BB * AL * DD;      // 245760
    float* den_part = v2 + BB * AL * DD;  // 32*32*10
    __hip_bfloat16* num_bf = (__hip_bfloat16*)(den_part + BB * CHUNKS * AL); // 7.86M bf16
    float* tpart = u;                 // overlay: consumed (k_tp2) before u is written (k_tattn)
    float* part  = (float*)num_bf;    // overlay: used only after k_poolvis consumed num_bf

    // cls token row
    hipMemcpyAsync(out, outp, (size_t)BB * DD * sizeof(float),
                   hipMemcpyDeviceToDevice, stream);

    k_pass1<<<dim3(CHUNKS, BB), 256, 0, stream>>>(outp, agent, layerp, num_bf, den_part);
    k_tp1<<<dim3(NC, 4), 256, 0, stream>>>(tfeat, tpart);
    k_tp2<<<NC, 256, 0, stream>>>(tpart, tfn);
    k_temb<<<dim3(NC, 3), 256, 0, stream>>>(tfn, wt, bt, temb);
    k_wtext<<<NC * AL, 64, 0, stream>>>(temb, agent, layerp, wtex);
    k_ptext<<<30, 256, 0, stream>>>(temb, wtex, ptex);
    k_mtextB10<<<dim3(AL, 3), 256, 0, stream>>>(ptex, wm, bm, agent, layerp, B10);
    k_poolvis<<<BB * AL, 256, 0, stream>>>(num_bf, den_part, pvis);
    // ag2 = pvis@wm.T + bm + B10[m%10]   (B10 = ptex@wm.T + bm + agent)
    k_gemmsk<<<dim3(12, 5, 4), 256, 0, stream>>>(pvis, wm, part);
    k_gemmred<<<320, 256, 0, stream>>>(part, bm, B10, ag2);
    k_tattn<<<dim3(AL, BB), 256, 0, stream>>>(ag2, temb, u);
    // v = u@w1.T + b1
    k_gemmsk<<<dim3(12, 5, 4), 256, 0, stream>>>(u, w1, part);
    k_gemmred<<<320, 256, 0, stream>>>(part, b1, nullptr, v);
    // v2 = v@w2.T + b2  (b2 folded exactly: softmax rows sum to 1)
    k_gemmsk<<<dim3(12, 5, 4), 256, 0, stream>>>(v, w2, part);
    k_gemmred<<<320, 256, 0, stream>>>(part, b2, nullptr, v2);
    k_pass2<<<dim3(CHUNKS, BB), 256, 0, stream>>>(outp, ag2, v2, ascale, out);
}